// Round 6
// baseline (1484.471 us; speedup 1.0000x reference)
//
#include <hip/hip_runtime.h>
#include <hip/hip_bf16.h>

typedef __hip_bfloat16 bf16;
typedef short v8s __attribute__((ext_vector_type(8)));
typedef float v4f __attribute__((ext_vector_type(4)));
typedef unsigned long long u64;

#define BATCH 256
#define SEQ 64
#define INPUT 512
#define HIDDEN 1024
#define CLASSES 1000

// ============================================================================
// Fragment-linear layouts (bf16):
//   A-chunk (16 m x 32 k): chunk[lane*8+j] = A[m16*16+(lane&15)][k32*32+(lane>>4)*8+j]
//   B-chunk (16 n x 32 k): chunk[lane*8+j] = W[k32*32+(lane>>4)*8+j][ncol]
// Xfrag:  [t][m16(16)][k32(16)][512]
// h-frag: [t][m16(16)][k32(32)][512]   (deep-buffered, write-once per address)
// Bf:     [hb(128)][n16l(2)][k32(NT)][512]; block hb covers h in [hb*8, hb*8+8):
//   n16l=0 cols = i-gate(8h), f-gate(8h); n16l=1 = g(8h), o(8h)
//   K-order: chunks 0..NE-1 = "early" tensor (L1: x; L2: own h2),
//            chunks NE..NE+31 = "late" tensor (h1 of matching t)
// Wof:    [n16(64)][k32(32)][512]
// ============================================================================

__global__ __launch_bounds__(256) void conv_x(const float* __restrict__ x,
                                              bf16* __restrict__ Xf) {
    int gid = blockIdx.x * 256 + threadIdx.x;
    int lane = gid & 63;
    int k32 = (gid >> 6) & 15;
    int m16 = (gid >> 10) & 15;
    int tt  = gid >> 14;
    int row = lane & 15, quad = lane >> 4;
    int b_ = m16 * 16 + row;
    int k  = k32 * 32 + quad * 8;
    const float* src = x + ((size_t)(b_ * SEQ + tt) * INPUT + k);
    float4 v0 = *(const float4*)src;
    float4 v1 = *(const float4*)(src + 4);
    bf16 o[8] = {__float2bfloat16(v0.x), __float2bfloat16(v0.y),
                 __float2bfloat16(v0.z), __float2bfloat16(v0.w),
                 __float2bfloat16(v1.x), __float2bfloat16(v1.y),
                 __float2bfloat16(v1.z), __float2bfloat16(v1.w)};
    bf16* dst = Xf + (size_t)(tt * 256 + m16 * 16 + k32) * 512 + lane * 8;
    *(v8s*)dst = *(v8s*)o;
}

// [W;U] fp32 -> Bf slices. grid (Ktot/64, 128, 2), block 256.
// K-order matches run_layer: L1 K0=512 puts x-part (W) first -> early ✓
// L2: early must be h2(t-1)@U, so U goes FIRST (swap argument roles).
__global__ __launch_bounds__(256) void build_bf(const float* __restrict__ Wfirst,
                                                const float* __restrict__ Wsecond,
                                                int K0, int NT,
                                                bf16* __restrict__ dst) {
    __shared__ float tile[64][17];
    const int kt = blockIdx.x, hb = blockIdx.y, n16l = blockIdx.z;
    const int k0 = kt * 64;
    const int tid = threadIdx.x;
#pragma unroll
    for (int i = 0; i < 4; i++) {
        int idx = tid + i * 256;
        int c = idx & 15, kl = idx >> 4;
        int k = k0 + kl;
        int srccol = (n16l * 2 + (c >> 3)) * 1024 + hb * 8 + (c & 7);
        float v = (k < K0) ? Wfirst[(size_t)k * 4096 + srccol]
                           : Wsecond[(size_t)(k - K0) * 4096 + srccol];
        tile[kl][c] = v;
    }
    __syncthreads();
    if (tid < 128) {
        int k32l = tid >> 6, l = tid & 63;
        bf16 o[8];
#pragma unroll
        for (int j = 0; j < 8; j++)
            o[j] = __float2bfloat16(tile[k32l * 32 + (l >> 4) * 8 + j][l & 15]);
        *(v8s*)(dst + ((size_t)(hb * 2 + n16l) * NT + kt * 2 + k32l) * 512 + l * 8) = *(v8s*)o;
    }
}

__global__ __launch_bounds__(256) void build_wof(const float* __restrict__ Wo,
                                                 bf16* __restrict__ dst) {
    __shared__ float tile[64][17];
    const int h16 = blockIdx.y, kt = blockIdx.x;
    const int k0 = kt * 64, nb = h16 * 16;
    const int tid = threadIdx.x;
#pragma unroll
    for (int i = 0; i < 4; i++) {
        int idx = tid + i * 256;
        int kl = idx >> 4, c = idx & 15;
        int k = k0 + kl;
        float v = (nb + c < CLASSES) ? Wo[(size_t)k * CLASSES + nb + c] : 0.f;
        tile[kl][c] = v;
    }
    __syncthreads();
    if (tid < 128) {
        int k32l = tid >> 6, l = tid & 63;
        int col = l & 15, quad = l >> 4;
        bf16 o[8];
#pragma unroll
        for (int j = 0; j < 8; j++)
            o[j] = __float2bfloat16(tile[k32l * 32 + quad * 8 + j][col]);
        int k32 = kt * 2 + k32l;
        *(v8s*)(dst + (size_t)(h16 * 32 + k32) * 512 + l * 8) = *(v8s*)o;
    }
}

// ---------------------------------------------------------------------------
__device__ __forceinline__ void spinwait(const int* p, int target) {
    while (__hip_atomic_load(p, __ATOMIC_RELAXED, __HIP_MEMORY_SCOPE_AGENT) < target)
        __builtin_amdgcn_s_sleep(1);
}
// Whole-wave gate: lane 0 spins (wave PC blocks), no block barrier.
__device__ __forceinline__ void wave_gate(const int* p, int target) {
    if ((threadIdx.x & 63) == 0) spinwait(p, target);
}

// One layer's 64-step recurrence. Block: 256 batch x 32 cols (8 h x 4 gates).
// Weights in LDS, c in registers, K-loop split into gated early/late halves.
template<int LAYER>
__device__ __forceinline__ void run_layer(
    const bf16* __restrict__ Xf,
    bf16* __restrict__ h1all, bf16* __restrict__ h2all,
    const bf16* __restrict__ hz,
    const bf16* __restrict__ Bl,      // LDS weights
    bf16* __restrict__ hstage,        // LDS 4 KB
    const float* __restrict__ bias,
    int hb,
    int* __restrict__ flags1, int* __restrict__ flags2)
{
    constexpr int NE = LAYER ? 32 : 16;    // early chunks
    constexpr int NL = 32;                 // late chunks
    constexpr int NT = NE + NL;
    const size_t HB = (size_t)BATCH * HIDDEN;

    bf16* hall = LAYER ? h2all : h1all;
    int* pub = LAYER ? flags2 : flags1;

    const int tid = threadIdx.x;
    const int lane = tid & 63, wave = tid >> 6;
    const int col = lane & 15, quad = lane >> 4;
    const bool hicol = (col & 8) != 0;
    const int K32 = hb >> 2, Q = hb & 3;

    const float bI = bias[0 * 1024 + hb * 8 + (col & 7)];
    const float bF = bias[1 * 1024 + hb * 8 + (col & 7)];
    const float bG = bias[2 * 1024 + hb * 8 + (col & 7)];
    const float bO = bias[3 * 1024 + hb * 8 + (col & 7)];

    float cc[4] = {0.f, 0.f, 0.f, 0.f};

    const bf16* bl0 = Bl + lane * 8;                     // n16l = 0
    const bf16* bl1 = Bl + (size_t)NT * 512 + lane * 8;  // n16l = 1

    for (int t = 0; t < SEQ; t++) {
        // ---------- EARLY half (L1: x(t), ungated; L2: h2(t-1), own flag) ----
        const bf16* Ae;
        if constexpr (LAYER == 0) {
            Ae = Xf + (size_t)t * (BATCH * INPUT);
        } else {
            if (t > 0) {
                wave_gate(flags2 + (t - 1) * 64, 128);
                Ae = h2all + (size_t)(t - 1) * HB;
            } else Ae = hz;
        }
        const bf16* ae0 = Ae + (size_t)((wave * 2 + 0) * NE) * 512 + lane * 8;
        const bf16* ae1 = Ae + (size_t)((wave * 2 + 1) * NE) * 512 + lane * 8;

        v4f acc[2][2] = {};
        v8s ra[8][2], rb[4][2];

#pragma unroll
        for (int k = 0; k < 8; k++) {
            ra[k][0] = *(const v8s*)(ae0 + (size_t)k * 512);
            ra[k][1] = *(const v8s*)(ae1 + (size_t)k * 512);
        }
#pragma unroll
        for (int k = 0; k < 4; k++) {
            rb[k][0] = *(const v8s*)(bl0 + (size_t)k * 512);
            rb[k][1] = *(const v8s*)(bl1 + (size_t)k * 512);
        }
#pragma unroll
        for (int k = 0; k < NE; k++) {
            const int sa = k & 7, sb = k & 3;
            acc[0][0] = __builtin_amdgcn_mfma_f32_16x16x32_bf16(ra[sa][0], rb[sb][0], acc[0][0], 0, 0, 0);
            acc[0][1] = __builtin_amdgcn_mfma_f32_16x16x32_bf16(ra[sa][0], rb[sb][1], acc[0][1], 0, 0, 0);
            acc[1][0] = __builtin_amdgcn_mfma_f32_16x16x32_bf16(ra[sa][1], rb[sb][0], acc[1][0], 0, 0, 0);
            acc[1][1] = __builtin_amdgcn_mfma_f32_16x16x32_bf16(ra[sa][1], rb[sb][1], acc[1][1], 0, 0, 0);
            if (k + 8 < NE) {
                ra[sa][0] = *(const v8s*)(ae0 + (size_t)(k + 8) * 512);
                ra[sa][1] = *(const v8s*)(ae1 + (size_t)(k + 8) * 512);
            }
            if (k + 4 < NE) {
                rb[sb][0] = *(const v8s*)(bl0 + (size_t)(k + 4) * 512);
                rb[sb][1] = *(const v8s*)(bl1 + (size_t)(k + 4) * 512);
            }
        }

        // ---------- LATE half (h1 of matching t; gated on flags1) ----------
        const bf16* Al;
        if constexpr (LAYER == 0) {
            if (t > 0) {
                wave_gate(flags1 + (t - 1) * 64, 128);
                Al = h1all + (size_t)(t - 1) * HB;
            } else Al = hz;
        } else {
            wave_gate(flags1 + t * 64, 128);
            Al = h1all + (size_t)t * HB;
        }
        const bf16* al0 = Al + (size_t)((wave * 2 + 0) * 32) * 512 + lane * 8;
        const bf16* al1 = Al + (size_t)((wave * 2 + 1) * 32) * 512 + lane * 8;
        const bf16* blL0 = bl0 + (size_t)NE * 512;
        const bf16* blL1 = bl1 + (size_t)NE * 512;

#pragma unroll
        for (int k = 0; k < 8; k++) {
            ra[k][0] = *(const v8s*)(al0 + (size_t)k * 512);
            ra[k][1] = *(const v8s*)(al1 + (size_t)k * 512);
        }
#pragma unroll
        for (int k = 0; k < 4; k++) {
            rb[k][0] = *(const v8s*)(blL0 + (size_t)k * 512);
            rb[k][1] = *(const v8s*)(blL1 + (size_t)k * 512);
        }
#pragma unroll
        for (int k = 0; k < NL; k++) {
            const int sa = k & 7, sb = k & 3;
            acc[0][0] = __builtin_amdgcn_mfma_f32_16x16x32_bf16(ra[sa][0], rb[sb][0], acc[0][0], 0, 0, 0);
            acc[0][1] = __builtin_amdgcn_mfma_f32_16x16x32_bf16(ra[sa][0], rb[sb][1], acc[0][1], 0, 0, 0);
            acc[1][0] = __builtin_amdgcn_mfma_f32_16x16x32_bf16(ra[sa][1], rb[sb][0], acc[1][0], 0, 0, 0);
            acc[1][1] = __builtin_amdgcn_mfma_f32_16x16x32_bf16(ra[sa][1], rb[sb][1], acc[1][1], 0, 0, 0);
            if (k + 8 < NL) {
                ra[sa][0] = *(const v8s*)(al0 + (size_t)(k + 8) * 512);
                ra[sa][1] = *(const v8s*)(al1 + (size_t)(k + 8) * 512);
            }
            if (k + 4 < NL) {
                rb[sb][0] = *(const v8s*)(blL0 + (size_t)(k + 4) * 512);
                rb[sb][1] = *(const v8s*)(blL1 + (size_t)(k + 4) * 512);
            }
        }

        // ---- epilogue: lane^8 gate exchange, register cell, LDS h-transpose ----
#pragma unroll
        for (int r = 0; r < 4; r++) {
            float send0 = hicol ? acc[0][0][r] : acc[1][0][r];
            float send1 = hicol ? acc[0][1][r] : acc[1][1][r];
            float recv0 = __shfl_xor(send0, 8, 64);
            float recv1 = __shfl_xor(send1, 8, 64);
            float own0 = hicol ? acc[1][0][r] : acc[0][0][r];
            float own1 = hicol ? acc[1][1][r] : acc[0][1][r];
            float zi = (hicol ? recv0 : own0) + bI;
            float zf = (hicol ? own0 : recv0) + bF;
            float zg = (hicol ? recv1 : own1) + bG;
            float zo = (hicol ? own1 : recv1) + bO;
            float ig = 1.f / (1.f + __expf(-zi));
            float fg = 1.f / (1.f + __expf(-zf));
            float e2g = __expf(2.f * zg);
            float gg = (e2g - 1.f) / (e2g + 1.f);
            float og = 1.f / (1.f + __expf(-zo));
            float cn = fg * cc[r] + ig * gg;
            float e2c = __expf(2.f * cn);
            float th = (e2c - 1.f) / (e2c + 1.f);
            cc[r] = cn;
            int m_local = wave * 32 + (hicol ? 16 : 0) + quad * 4 + r;
            hstage[m_local * 8 + (col & 7)] = __float2bfloat16(og * th);
        }
        // wave-private transpose rows -> write-through h store (16 B/lane<32)
        if (lane < 32) {
            int row = wave * 32 + lane;
            v8s hv = *(const v8s*)(hstage + row * 8);
            bf16* houtt = hall + (size_t)t * HB;
            size_t eoff = ((size_t)(row >> 4) * 32 + K32) * 512
                        + (size_t)((row & 15) + 16 * Q) * 8;
            u64 qq[2];
            *(v8s*)qq = hv;
            u64* dp = (u64*)(houtt + eoff);
            __hip_atomic_store(dp,     qq[0], __ATOMIC_RELAXED, __HIP_MEMORY_SCOPE_AGENT);
            __hip_atomic_store(dp + 1, qq[1], __ATOMIC_RELAXED, __HIP_MEMORY_SCOPE_AGENT);
        }
        __syncthreads();   // every wave drains vmcnt before tid0 publishes

        if (tid == 0)
            __hip_atomic_fetch_add(pub + t * 64, 1,
                                   __ATOMIC_RELAXED, __HIP_MEMORY_SCOPE_AGENT);
    }
}

__global__ __launch_bounds__(512, 2) void lstm_persist(
    const bf16* __restrict__ Xf,
    const bf16* __restrict__ Bf1, const bf16* __restrict__ Bf2,
    const float* __restrict__ b1, const float* __restrict__ b2,
    bf16* __restrict__ h1all, bf16* __restrict__ h2all,
    const bf16* __restrict__ hz,
    int* __restrict__ flags1, int* __restrict__ flags2)
{
    extern __shared__ char smem[];
    bf16* Bl = (bf16*)smem;
    bf16* hstage = (bf16*)(smem + 131072);

    const int b = blockIdx.x;
    const int layer = b >> 7;
    const int hb = b & 127;
    const int tid = threadIdx.x;

    {
        const int NTl = layer ? 64 : 48;
        const bf16* Bsrc = (layer ? Bf2 : Bf1) + (size_t)(hb * 2 * NTl) * 512;
        const int nbytes = NTl * 2 * 1024;
        for (int o = tid * 16; o < nbytes; o += 512 * 16)
            *(uint4*)(smem + o) = *(const uint4*)((const char*)Bsrc + o);
    }
    __syncthreads();

    if (layer == 0)
        run_layer<0>(Xf, h1all, h2all, hz, Bl, hstage, b1, hb, flags1, flags2);
    else
        run_layer<1>(Xf, h1all, h2all, hz, Bl, hstage, b2, hb, flags1, flags2);
}

// ---------------- projection: out = h2(63) @ Wo + bo ----------------
__global__ __launch_bounds__(256, 2) void proj_kernel(
    const bf16* __restrict__ H,
    const bf16* __restrict__ Wof,
    const float* __restrict__ bo,
    float* __restrict__ Out)
{
    const int mblk = blockIdx.x, nblk = blockIdx.y;
    const int tid = threadIdx.x;
    const int lane = tid & 63;
    const int wave = tid >> 6;
    const int mw = wave >> 1, nw = wave & 1;
    const int col = lane & 15, quad = lane >> 4;

    const int m16 = mblk * 4 + mw * 2;
    const bf16* ah0 = H + (size_t)(m16 * 32) * 512 + lane * 8;
    const bf16* ah1 = H + (size_t)((m16 + 1) * 32) * 512 + lane * 8;
    const int n16a = nblk * 4 + nw * 2, n16b = n16a + 1;
    const bf16* bb0 = Wof + (size_t)(n16a * 32) * 512 + lane * 8;
    const bf16* bb1 = Wof + (size_t)(n16b * 32) * 512 + lane * 8;

    v4f acc00{}, acc01{}, acc10{}, acc11{};
    v8s ra0[8], ra1[8], rb0[8], rb1[8];

#define ISSUE(KK, SLOT) do {                          \
    const int kk_ = (KK);                             \
    ra0[SLOT] = *(const v8s*)(ah0 + kk_ * 512);       \
    ra1[SLOT] = *(const v8s*)(ah1 + kk_ * 512);       \
    rb0[SLOT] = *(const v8s*)(bb0 + kk_ * 512);       \
    rb1[SLOT] = *(const v8s*)(bb1 + kk_ * 512);       \
} while (0)

#pragma unroll
    for (int u = 0; u < 8; u++) ISSUE(u, u);

    for (int base = 0; base < 32; base += 8) {
#pragma unroll
        for (int u = 0; u < 8; u++) {
            acc00 = __builtin_amdgcn_mfma_f32_16x16x32_bf16(ra0[u], rb0[u], acc00, 0, 0, 0);
            acc01 = __builtin_amdgcn_mfma_f32_16x16x32_bf16(ra0[u], rb1[u], acc01, 0, 0, 0);
            acc10 = __builtin_amdgcn_mfma_f32_16x16x32_bf16(ra1[u], rb0[u], acc10, 0, 0, 0);
            acc11 = __builtin_amdgcn_mfma_f32_16x16x32_bf16(ra1[u], rb1[u], acc11, 0, 0, 0);
            const int k2 = base + u + 8;
            if (k2 < 32) ISSUE(k2, u);
        }
    }
#undef ISSUE

    const int n0 = n16a * 16 + col, n1 = n16b * 16 + col;
    const float bo0 = (n0 < CLASSES) ? bo[n0] : 0.f;
    const float bo1 = (n1 < CLASSES) ? bo[n1] : 0.f;
#pragma unroll
    for (int i = 0; i < 2; i++) {
        const int row = mblk * 64 + mw * 32 + i * 16 + quad * 4;
        v4f a0 = i ? acc10 : acc00;
        v4f a1 = i ? acc11 : acc01;
#pragma unroll
        for (int r = 0; r < 4; r++) {
            if (n0 < CLASSES) Out[(size_t)(row + r) * CLASSES + n0] = a0[r] + bo0;
            if (n1 < CLASSES) Out[(size_t)(row + r) * CLASSES + n1] = a1[r] + bo1;
        }
    }
}

// ---------------- launcher ----------------
extern "C" void kernel_launch(void* const* d_in, const int* in_sizes, int n_in,
                              void* d_out, int out_size, void* d_ws, size_t ws_size,
                              hipStream_t stream) {
    const float* x  = (const float*)d_in[0];
    const float* W1 = (const float*)d_in[1];
    const float* U1 = (const float*)d_in[2];
    const float* b1 = (const float*)d_in[3];
    const float* W2 = (const float*)d_in[4];
    const float* U2 = (const float*)d_in[5];
    const float* b2 = (const float*)d_in[6];
    const float* Wo = (const float*)d_in[7];
    const float* bo = (const float*)d_in[8];
    float* out = (float*)d_out;

    char* ws = (char*)d_ws;
    size_t off = 0;
    auto alloc = [&](size_t bytes) -> void* {
        void* p = ws + off;
        off += (bytes + 255) & ~(size_t)255;
        return p;
    };
    bf16* Xf    = (bf16*)alloc((size_t)SEQ * BATCH * INPUT * 2);   // 16.8 MB
    bf16* Bf1   = (bf16*)alloc((size_t)128 * 2 * 48 * 512 * 2);    // 12.6 MB
    bf16* Bf2   = (bf16*)alloc((size_t)128 * 2 * 64 * 512 * 2);    // 16.8 MB
    bf16* Wof   = (bf16*)alloc((size_t)64 * 32 * 512 * 2);         // 2 MB
    bf16* h1all = (bf16*)alloc((size_t)SEQ * BATCH * HIDDEN * 2);  // 33.6 MB
    bf16* h2all = (bf16*)alloc((size_t)SEQ * BATCH * HIDDEN * 2);  // 33.6 MB
    bf16* hz    = (bf16*)alloc((size_t)BATCH * HIDDEN * 2);
    int* flags1 = (int*)alloc(64 * 64 * 4);
    int* flags2 = (int*)alloc(64 * 64 * 4);

    hipMemsetAsync(hz, 0, (size_t)BATCH * HIDDEN * 2, stream);
    hipMemsetAsync(flags1, 0, 64 * 64 * 4, stream);
    hipMemsetAsync(flags2, 0, 64 * 64 * 4, stream);

    conv_x<<<4096, 256, 0, stream>>>(x, Xf);
    // L1: x-part (W1) first = early, h-part (U1) late
    build_bf<<<dim3(24, 128, 2), 256, 0, stream>>>(W1, U1, 512, 48, Bf1);
    // L2: own-h part (U2) FIRST = early, h1-part (W2) late
    build_bf<<<dim3(32, 128, 2), 256, 0, stream>>>(U2, W2, 1024, 64, Bf2);
    build_wof<<<dim3(16, 64), 256, 0, stream>>>(Wo, Wof);

    lstm_persist<<<256, 512, 135168, stream>>>(Xf, Bf1, Bf2, b1, b2,
                                               h1all, h2all, hz, flags1, flags2);

    proj_kernel<<<dim3(4, 16), 256, 0, stream>>>(
        h2all + (size_t)(SEQ - 1) * BATCH * HIDDEN, Wof, bo, out);
}

// Round 7
// 1153.435 us; speedup vs baseline: 1.2870x; 1.2870x over previous
//
#include <hip/hip_runtime.h>
#include <hip/hip_bf16.h>

typedef __hip_bfloat16 bf16;
typedef short v8s __attribute__((ext_vector_type(8)));
typedef float v4f __attribute__((ext_vector_type(4)));
typedef unsigned long long u64;

#define BATCH 256
#define SEQ 64
#define INPUT 512
#define HIDDEN 1024
#define CLASSES 1000

// ============================================================================
// Fragment-linear layouts (bf16):
//   A-chunk (16 m x 32 k): chunk[lane*8+j] = A[m16*16+(lane&15)][k32*32+(lane>>4)*8+j]
//   B-chunk (16 n x 32 k): chunk[lane*8+j] = W[k32*32+(lane>>4)*8+j][ncol]
// Xfrag:  [t][m16(16)][k32(16)][512]
// h-frag: [t][m16(16)][k32(32)][512]   (deep-buffered, write-once per address)
// Bf:     [hb(128)][n16l(2)][k32(NT)][512]; block hb covers h in [hb*8, hb*8+8):
//   n16l=0 cols = i-gate(8h), f-gate(8h); n16l=1 = g(8h), o(8h)
// Wof:    [n16(64)][k32(32)][512]
// ============================================================================

__global__ __launch_bounds__(256) void conv_x(const float* __restrict__ x,
                                              bf16* __restrict__ Xf) {
    int gid = blockIdx.x * 256 + threadIdx.x;
    int lane = gid & 63;
    int k32 = (gid >> 6) & 15;
    int m16 = (gid >> 10) & 15;
    int tt  = gid >> 14;
    int row = lane & 15, quad = lane >> 4;
    int b_ = m16 * 16 + row;
    int k  = k32 * 32 + quad * 8;
    const float* src = x + ((size_t)(b_ * SEQ + tt) * INPUT + k);
    float4 v0 = *(const float4*)src;
    float4 v1 = *(const float4*)(src + 4);
    bf16 o[8] = {__float2bfloat16(v0.x), __float2bfloat16(v0.y),
                 __float2bfloat16(v0.z), __float2bfloat16(v0.w),
                 __float2bfloat16(v1.x), __float2bfloat16(v1.y),
                 __float2bfloat16(v1.z), __float2bfloat16(v1.w)};
    bf16* dst = Xf + (size_t)(tt * 256 + m16 * 16 + k32) * 512 + lane * 8;
    *(v8s*)dst = *(v8s*)o;
}

// [W;U] fp32 -> Bf slices. grid (Ktot/64, 128, 2), block 256.
__global__ __launch_bounds__(256) void build_bf(const float* __restrict__ W,
                                                const float* __restrict__ U,
                                                int K0, int NT,
                                                bf16* __restrict__ dst) {
    __shared__ float tile[64][17];
    const int kt = blockIdx.x, hb = blockIdx.y, n16l = blockIdx.z;
    const int k0 = kt * 64;
    const int tid = threadIdx.x;
#pragma unroll
    for (int i = 0; i < 4; i++) {
        int idx = tid + i * 256;
        int c = idx & 15, kl = idx >> 4;
        int k = k0 + kl;
        int srccol = (n16l * 2 + (c >> 3)) * 1024 + hb * 8 + (c & 7);
        float v = (k < K0) ? W[(size_t)k * 4096 + srccol]
                           : U[(size_t)(k - K0) * 4096 + srccol];
        tile[kl][c] = v;
    }
    __syncthreads();
    if (tid < 128) {
        int k32l = tid >> 6, l = tid & 63;
        bf16 o[8];
#pragma unroll
        for (int j = 0; j < 8; j++)
            o[j] = __float2bfloat16(tile[k32l * 32 + (l >> 4) * 8 + j][l & 15]);
        *(v8s*)(dst + ((size_t)(hb * 2 + n16l) * NT + kt * 2 + k32l) * 512 + l * 8) = *(v8s*)o;
    }
}

__global__ __launch_bounds__(256) void build_wof(const float* __restrict__ Wo,
                                                 bf16* __restrict__ dst) {
    __shared__ float tile[64][17];
    const int h16 = blockIdx.y, kt = blockIdx.x;
    const int k0 = kt * 64, nb = h16 * 16;
    const int tid = threadIdx.x;
#pragma unroll
    for (int i = 0; i < 4; i++) {
        int idx = tid + i * 256;
        int kl = idx >> 4, c = idx & 15;
        int k = k0 + kl;
        float v = (nb + c < CLASSES) ? Wo[(size_t)k * CLASSES + nb + c] : 0.f;
        tile[kl][c] = v;
    }
    __syncthreads();
    if (tid < 128) {
        int k32l = tid >> 6, l = tid & 63;
        int col = l & 15, quad = l >> 4;
        bf16 o[8];
#pragma unroll
        for (int j = 0; j < 8; j++)
            o[j] = __float2bfloat16(tile[k32l * 32 + quad * 8 + j][col]);
        int k32 = kt * 2 + k32l;
        *(v8s*)(dst + (size_t)(h16 * 32 + k32) * 512 + l * 8) = *(v8s*)o;
    }
}

// ---------------------------------------------------------------------------
__device__ __forceinline__ void spinwait(const int* p, int target) {
    while (__hip_atomic_load(p, __ATOMIC_RELAXED, __HIP_MEMORY_SCOPE_AGENT) < target)
        __builtin_amdgcn_s_sleep(1);
}

// One layer's full 64-step recurrence. Block tile: 256 batch x 32 cols
// (8 h x 4 gates). Weights in LDS, c-state in registers.
// K-loop: groups of 8 chunks, double-buffered A-prefetch in registers,
// sched_barrier(0) pins load-issue order (prevents the compiler sinking
// the ring to just-before-use, which collapsed VGPR use to 48 in round 5).
template<int NT, int NA>
__device__ __forceinline__ void run_layer(
    const bf16* __restrict__ A0all, size_t A0stride,
    bf16* __restrict__ hall,
    const bf16* __restrict__ hz,
    const bf16* __restrict__ Bl,
    bf16* __restrict__ hstage,
    const float* __restrict__ bias,
    int hb,
    const int* __restrict__ waitA,
    const int* __restrict__ waitSelf,
    int* __restrict__ pub)
{
    constexpr int G = 8;
    constexpr int NG = NT / G;
    const size_t HB = (size_t)BATCH * HIDDEN;
    const int tid = threadIdx.x;
    const int lane = tid & 63, wave = tid >> 6;
    const int col = lane & 15, quad = lane >> 4;
    const bool hicol = (col & 8) != 0;
    const int K32 = hb >> 2, Q = hb & 3;

    const float bI = bias[0 * 1024 + hb * 8 + (col & 7)];
    const float bF = bias[1 * 1024 + hb * 8 + (col & 7)];
    const float bG = bias[2 * 1024 + hb * 8 + (col & 7)];
    const float bO = bias[3 * 1024 + hb * 8 + (col & 7)];

    float cc[4] = {0.f, 0.f, 0.f, 0.f};   // cell state in registers, all 64 steps

    const bf16* bl0 = Bl + lane * 8;
    const bf16* bl1 = Bl + (size_t)NT * 512 + lane * 8;

    for (int t = 0; t < SEQ; t++) {
        if (tid == 0) {
            if (waitA) spinwait(waitA + t * 64, 128);
            if (t > 0) spinwait(waitSelf + (t - 1) * 64, 128);
        }
        __syncthreads();

        const bf16* A0 = A0all + (size_t)t * A0stride;
        const bf16* A1 = t ? (hall + (size_t)(t - 1) * HB) : hz;
        const bf16* ax0 = A0 + (size_t)((wave * 2 + 0) * NA) * 512 + lane * 8;
        const bf16* ax1 = A0 + (size_t)((wave * 2 + 1) * NA) * 512 + lane * 8;
        const bf16* ah0 = A1 + (size_t)((wave * 2 + 0) * 32) * 512 + lane * 8;
        const bf16* ah1 = A1 + (size_t)((wave * 2 + 1) * 32) * 512 + lane * 8;

        v4f acc[2][2] = {};
        v8s bufA[2][G][2];     // ping-pong group buffers (128 VGPRs) — the ring

#define LOADG(GI, PP) do {                                                       \
    _Pragma("unroll")                                                            \
    for (int j_ = 0; j_ < G; j_++) {                                             \
        const int k_ = (GI) * G + j_;                                            \
        bufA[PP][j_][0] = *(const v8s*)((k_ < NA) ? (ax0 + (size_t)k_ * 512)     \
                                         : (ah0 + (size_t)(k_ - NA) * 512));     \
        bufA[PP][j_][1] = *(const v8s*)((k_ < NA) ? (ax1 + (size_t)k_ * 512)     \
                                         : (ah1 + (size_t)(k_ - NA) * 512));     \
    }                                                                            \
} while (0)

        LOADG(0, 0);

#pragma unroll
        for (int g = 0; g < NG; g++) {
            if (g + 1 < NG) {
                if (((g + 1) & 1) == 0) LOADG(g + 1, 0); else LOADG(g + 1, 1);
            }
            __builtin_amdgcn_sched_barrier(0);   // pin: next group's loads issue
                                                 // before this group's MFMAs
#pragma unroll
            for (int j = 0; j < G; j++) {
                const int k = g * G + j;
                const int pp = g & 1;
                v8s b0 = *(const v8s*)(bl0 + (size_t)k * 512);
                v8s b1 = *(const v8s*)(bl1 + (size_t)k * 512);
                acc[0][0] = __builtin_amdgcn_mfma_f32_16x16x32_bf16(bufA[pp][j][0], b0, acc[0][0], 0, 0, 0);
                acc[0][1] = __builtin_amdgcn_mfma_f32_16x16x32_bf16(bufA[pp][j][0], b1, acc[0][1], 0, 0, 0);
                acc[1][0] = __builtin_amdgcn_mfma_f32_16x16x32_bf16(bufA[pp][j][1], b0, acc[1][0], 0, 0, 0);
                acc[1][1] = __builtin_amdgcn_mfma_f32_16x16x32_bf16(bufA[pp][j][1], b1, acc[1][1], 0, 0, 0);
            }
        }
#undef LOADG

        // ---- epilogue: lane^8 gate exchange, register cell, LDS h-transpose ----
#pragma unroll
        for (int r = 0; r < 4; r++) {
            float send0 = hicol ? acc[0][0][r] : acc[1][0][r];
            float send1 = hicol ? acc[0][1][r] : acc[1][1][r];
            float recv0 = __shfl_xor(send0, 8, 64);
            float recv1 = __shfl_xor(send1, 8, 64);
            float own0 = hicol ? acc[1][0][r] : acc[0][0][r];
            float own1 = hicol ? acc[1][1][r] : acc[0][1][r];
            float zi = (hicol ? recv0 : own0) + bI;
            float zf = (hicol ? own0 : recv0) + bF;
            float zg = (hicol ? recv1 : own1) + bG;
            float zo = (hicol ? own1 : recv1) + bO;
            float ig = 1.f / (1.f + __expf(-zi));
            float fg = 1.f / (1.f + __expf(-zf));
            float e2g = __expf(2.f * zg);
            float gg = (e2g - 1.f) / (e2g + 1.f);
            float og = 1.f / (1.f + __expf(-zo));
            float cn = fg * cc[r] + ig * gg;
            float e2c = __expf(2.f * cn);
            float th = (e2c - 1.f) / (e2c + 1.f);
            cc[r] = cn;
            int m_local = wave * 32 + (hicol ? 16 : 0) + quad * 4 + r;
            hstage[m_local * 8 + (col & 7)] = __float2bfloat16(og * th);
        }
        // wave-private transpose rows -> write-through h store (16 B per lane<32)
        if (lane < 32) {
            int row = wave * 32 + lane;
            v8s hv = *(const v8s*)(hstage + row * 8);
            bf16* houtt = hall + (size_t)t * HB;
            size_t eoff = ((size_t)(row >> 4) * 32 + K32) * 512
                        + (size_t)((row & 15) + 16 * Q) * 8;
            u64 qq[2];
            *(v8s*)qq = hv;
            u64* dp = (u64*)(houtt + eoff);
            __hip_atomic_store(dp,     qq[0], __ATOMIC_RELAXED, __HIP_MEMORY_SCOPE_AGENT);
            __hip_atomic_store(dp + 1, qq[1], __ATOMIC_RELAXED, __HIP_MEMORY_SCOPE_AGENT);
        }
        __syncthreads();   // all waves drain vmcnt before publish

        if (tid == 0)
            __hip_atomic_fetch_add(pub + t * 64, 1,
                                   __ATOMIC_RELAXED, __HIP_MEMORY_SCOPE_AGENT);
    }
}

__global__ __launch_bounds__(512, 2) void lstm_persist(
    const bf16* __restrict__ Xf,
    const bf16* __restrict__ Bf1, const bf16* __restrict__ Bf2,
    const float* __restrict__ b1, const float* __restrict__ b2,
    bf16* __restrict__ h1all, bf16* __restrict__ h2all,
    const bf16* __restrict__ hz,
    int* __restrict__ flags1, int* __restrict__ flags2)
{
    extern __shared__ char smem[];
    bf16* Bl = (bf16*)smem;
    bf16* hstage = (bf16*)(smem + 131072);

    const int b = blockIdx.x;
    const int layer = b >> 7;
    const int hb = b & 127;
    const int tid = threadIdx.x;

    // one-time weight slice -> LDS (96 KB L1 / 128 KB L2)
    {
        const int NTl = layer ? 64 : 48;
        const bf16* Bsrc = (layer ? Bf2 : Bf1) + (size_t)(hb * 2 * NTl) * 512;
        const int nbytes = NTl * 2 * 1024;
        for (int o = tid * 16; o < nbytes; o += 512 * 16)
            *(uint4*)(smem + o) = *(const uint4*)((const char*)Bsrc + o);
    }
    __syncthreads();

    if (layer == 0)
        run_layer<48, 16>(Xf, (size_t)BATCH * INPUT, h1all, hz, Bl, hstage,
                          b1, hb, nullptr, flags1, flags1);
    else
        run_layer<64, 32>(h1all, (size_t)BATCH * HIDDEN, h2all, hz, Bl, hstage,
                          b2, hb, flags1, flags2, flags2);
}

// ---------------- projection: out = h2(63) @ Wo + bo ----------------
__global__ __launch_bounds__(256, 2) void proj_kernel(
    const bf16* __restrict__ H,
    const bf16* __restrict__ Wof,
    const float* __restrict__ bo,
    float* __restrict__ Out)
{
    const int mblk = blockIdx.x, nblk = blockIdx.y;
    const int tid = threadIdx.x;
    const int lane = tid & 63;
    const int wave = tid >> 6;
    const int mw = wave >> 1, nw = wave & 1;
    const int col = lane & 15, quad = lane >> 4;

    const int m16 = mblk * 4 + mw * 2;
    const bf16* ah0 = H + (size_t)(m16 * 32) * 512 + lane * 8;
    const bf16* ah1 = H + (size_t)((m16 + 1) * 32) * 512 + lane * 8;
    const int n16a = nblk * 4 + nw * 2, n16b = n16a + 1;
    const bf16* bb0 = Wof + (size_t)(n16a * 32) * 512 + lane * 8;
    const bf16* bb1 = Wof + (size_t)(n16b * 32) * 512 + lane * 8;

    v4f acc00{}, acc01{}, acc10{}, acc11{};
    v8s ra0[8], ra1[8], rb0[8], rb1[8];

#define ISSUE(KK, SLOT) do {                          \
    const int kk_ = (KK);                             \
    ra0[SLOT] = *(const v8s*)(ah0 + kk_ * 512);       \
    ra1[SLOT] = *(const v8s*)(ah1 + kk_ * 512);       \
    rb0[SLOT] = *(const v8s*)(bb0 + kk_ * 512);       \
    rb1[SLOT] = *(const v8s*)(bb1 + kk_ * 512);       \
} while (0)

#pragma unroll
    for (int u = 0; u < 8; u++) ISSUE(u, u);

    for (int base = 0; base < 32; base += 8) {
#pragma unroll
        for (int u = 0; u < 8; u++) {
            acc00 = __builtin_amdgcn_mfma_f32_16x16x32_bf16(ra0[u], rb0[u], acc00, 0, 0, 0);
            acc01 = __builtin_amdgcn_mfma_f32_16x16x32_bf16(ra0[u], rb1[u], acc01, 0, 0, 0);
            acc10 = __builtin_amdgcn_mfma_f32_16x16x32_bf16(ra1[u], rb0[u], acc10, 0, 0, 0);
            acc11 = __builtin_amdgcn_mfma_f32_16x16x32_bf16(ra1[u], rb1[u], acc11, 0, 0, 0);
            const int k2 = base + u + 8;
            if (k2 < 32) ISSUE(k2, u);
        }
    }
#undef ISSUE

    const int n0 = n16a * 16 + col, n1 = n16b * 16 + col;
    const float bo0 = (n0 < CLASSES) ? bo[n0] : 0.f;
    const float bo1 = (n1 < CLASSES) ? bo[n1] : 0.f;
#pragma unroll
    for (int i = 0; i < 2; i++) {
        const int row = mblk * 64 + mw * 32 + i * 16 + quad * 4;
        v4f a0 = i ? acc10 : acc00;
        v4f a1 = i ? acc11 : acc01;
#pragma unroll
        for (int r = 0; r < 4; r++) {
            if (n0 < CLASSES) Out[(size_t)(row + r) * CLASSES + n0] = a0[r] + bo0;
            if (n1 < CLASSES) Out[(size_t)(row + r) * CLASSES + n1] = a1[r] + bo1;
        }
    }
}

// ---------------- launcher ----------------
extern "C" void kernel_launch(void* const* d_in, const int* in_sizes, int n_in,
                              void* d_out, int out_size, void* d_ws, size_t ws_size,
                              hipStream_t stream) {
    const float* x  = (const float*)d_in[0];
    const float* W1 = (const float*)d_in[1];
    const float* U1 = (const float*)d_in[2];
    const float* b1 = (const float*)d_in[3];
    const float* W2 = (const float*)d_in[4];
    const float* U2 = (const float*)d_in[5];
    const float* b2 = (const float*)d_in[6];
    const float* Wo = (const float*)d_in[7];
    const float* bo = (const float*)d_in[8];
    float* out = (float*)d_out;

    char* ws = (char*)d_ws;
    size_t off = 0;
    auto alloc = [&](size_t bytes) -> void* {
        void* p = ws + off;
        off += (bytes + 255) & ~(size_t)255;
        return p;
    };
    bf16* Xf    = (bf16*)alloc((size_t)SEQ * BATCH * INPUT * 2);   // 16.8 MB
    bf16* Bf1   = (bf16*)alloc((size_t)128 * 2 * 48 * 512 * 2);    // 12.6 MB
    bf16* Bf2   = (bf16*)alloc((size_t)128 * 2 * 64 * 512 * 2);    // 16.8 MB
    bf16* Wof   = (bf16*)alloc((size_t)64 * 32 * 512 * 2);         // 2 MB
    bf16* h1all = (bf16*)alloc((size_t)SEQ * BATCH * HIDDEN * 2);  // 33.6 MB
    bf16* h2all = (bf16*)alloc((size_t)SEQ * BATCH * HIDDEN * 2);  // 33.6 MB
    bf16* hz    = (bf16*)alloc((size_t)BATCH * HIDDEN * 2);
    int* flags1 = (int*)alloc(64 * 64 * 4);
    int* flags2 = (int*)alloc(64 * 64 * 4);

    hipMemsetAsync(hz, 0, (size_t)BATCH * HIDDEN * 2, stream);
    hipMemsetAsync(flags1, 0, 64 * 64 * 4, stream);
    hipMemsetAsync(flags2, 0, 64 * 64 * 4, stream);

    conv_x<<<4096, 256, 0, stream>>>(x, Xf);
    build_bf<<<dim3(24, 128, 2), 256, 0, stream>>>(W1, U1, 512, 48, Bf1);
    build_bf<<<dim3(32, 128, 2), 256, 0, stream>>>(W2, U2, 1024, 64, Bf2);
    build_wof<<<dim3(16, 64), 256, 0, stream>>>(Wo, Wof);

    lstm_persist<<<256, 512, 135168, stream>>>(Xf, Bf1, Bf2, b1, b2,
                                               h1all, h2all, hz, flags1, flags2);

    proj_kernel<<<dim3(4, 16), 256, 0, stream>>>(
        h2all + (size_t)(SEQ - 1) * BATCH * HIDDEN, Wof, bo, out);
}